// Round 20
// baseline (104.965 us; speedup 1.0000x reference)
//
#include <hip/hip_runtime.h>
#include <hip/hip_bf16.h>

// Problem constants: E=1024, H=16, HD=64, T=1024, B=4, S=1024.
// d_out: attn(T,B,E) f32 [4M floats] then avg_w(B,T,S) f32 [4M floats].
// ws layout (bytes): qh 0..8M (head-major [bh][t][64], q pre-scaled 0.125*log2e),
//   kh 8..16M, vf 24..32M (frag-swizzled V, proj cmode3 LDS-coalesced epilogue),
//   ab 32..40M, WT 40..46M, owb 46..48M.
// q/k/v f32 inputs consumed DIRECTLY by gemm_proj via global_load_lds into f32
// LDS tiles (chunk-XOR swizzle c^=row&7; conversion at fragment-read).
// avg_w computed inside the attn launch (blocks >= 1024) for overlap.

typedef __bf16 bf16;
typedef float f32x4 __attribute__((ext_vector_type(4)));
typedef float float4v __attribute__((ext_vector_type(4)));
typedef bf16 bf16x8 __attribute__((ext_vector_type(8)));
typedef bf16 bf16x4 __attribute__((ext_vector_type(4)));

#define LOG2E 1.4426950408889634f

// async global->LDS, 16B/lane; dst base wave-uniform (HW adds lane*16).
__device__ __forceinline__ void gll16(const void* g, void* l) {
  __builtin_amdgcn_global_load_lds(
      (const __attribute__((address_space(1))) void*)g,
      (__attribute__((address_space(3))) void*)l, 16, 0, 0);
}

// XCD-chunked swizzle: consecutive works (sharing an A-panel) land on one XCD.
__device__ __forceinline__ int xcd_swz(int flat, int nwg) {
  int q = nwg >> 3;
  return (flat & 7) * q + (flat >> 3);
}

__device__ __forceinline__ bf16x4 cvt4(float4v v) {
  bf16x4 b = { (bf16)v.x, (bf16)v.y, (bf16)v.z, (bf16)v.w };
  return b;
}

// ---------------- prep kernel (W transpose + out_w conv only) ----------------
__global__ __launch_bounds__(256) void prep_all(
    const float* __restrict__ W, const float* __restrict__ out_w,
    bf16* __restrict__ WT, bf16* __restrict__ owb) {
  __shared__ bf16 tile[64][72];
  int bid = blockIdx.x;
  if (bid >= 768) {  // out_w conversion: 1024 blocks
    int i = ((bid - 768) * 256 + (int)threadIdx.x) * 4;
    float4v v = *(const float4v*)(out_w + i);
    *(bf16x4*)&owb[i] = cvt4(v);
    return;
  }
  // W transpose: dst[sec][j][i] = (bf16) src[sec*1024 + i][j]
  int sec = bid >> 8, bx = bid & 15, by = (bid >> 4) & 15;
  int i0 = by * 64, j0 = bx * 64;
  const float* s = W + (long)sec * 1048576;
  bf16* d = WT + (long)sec * 1048576;
  int t = threadIdx.x;
#pragma unroll
  for (int p = 0; p < 4; p++) {
    int ri = (t >> 4) + p * 16, cj = (t & 15) * 4;
    float4v vv = *(const float4v*)(s + (long)(i0 + ri) * 1024 + j0 + cj);
    *(bf16x4*)&tile[ri][cj] = cvt4(vv);
  }
  __syncthreads();
#pragma unroll
  for (int p = 0; p < 4; p++) {
    int rj = (t >> 4) + p * 16, ci = (t & 15) * 4;
    bf16x4 bv = { tile[ci][rj], tile[ci + 1][rj], tile[ci + 2][rj], tile[ci + 3][rj] };
    *(bf16x4*)&d[(long)(j0 + rj) * 1024 + i0 + ci] = bv;
  }
}

// ---------------- unified NT GEMM core (512 thr, 8 waves, 128x128) ----------
// R11-best loop: dbuf, stage(next) BEFORE compute(cur), ONE __syncthreads per
// k-step; all staging via global_load_lds. AF32: A f32 staged into f32 LDS
// tiles with CHUNK-XOR swizzle (float4-chunk c stored at c^(row&7); read at
// (2g)^(r&7), (2g+1)^(r&7)) -> 8 slots x 8 lanes = conflict-free (fixes R19's
// 3.27M conflicts); converted f32->bf16 at fragment read.
// cmode: 0 f32 std, 1 bf16 std, 2 bf16 head-major via LDS-coalesced epilogue
// (8 contiguous 4KB spans; fixes the 2B-scatter), 3 vf fragment (LDS epi).
template <bool AF32>
__device__ __forceinline__ void gemm_core(
    const void* __restrict__ Av, long lda,
    const bf16* __restrict__ B, long ldb,
    void* __restrict__ C, long ldc,
    const float* __restrict__ bias, float scale, int K,
    int m0, int n0, int cmode) {
  __shared__ bf16 smem[AF32 ? 24576 : 16384];
  float* sAf = (float*)smem;                       // AF32: [2][4096] f32
  bf16* sBb = smem + (AF32 ? 16384 : 8192);        // [2][4096] bf16
  int t = threadIdx.x;
  int w = t >> 6, lane = t & 63, r = lane & 15, g = lane >> 4;
  int mq = (w >> 1) * 32, nq = (w & 1) * 64;
  int srow = w * 16 + (lane >> 2);
  int scol = ((lane & 3) ^ ((srow >> 1) & 3)) * 8;
  int fsw = (r >> 1) & 3;
  const bf16* Bs = B + (long)(n0 + srow) * ldb + scol;
  const bf16* As = (const bf16*)Av + (long)(m0 + srow) * lda + scol;  // !AF32
  // AF32 staging: lane l stages float4-chunk (l&7) of row w*16+(l>>3) (+8 on
  // 2nd gll); the chunk LANDING at position l&7 is logical chunk (l&7)^(l>>3).
  int aro = lane >> 3;
  int acolf = 4 * ((lane & 7) ^ aro);
  const float* Af = (const float*)Av + (long)(m0 + w * 16 + aro) * lda + acolf;

  f32x4 acc[2][4];
#pragma unroll
  for (int mi = 0; mi < 2; mi++)
#pragma unroll
    for (int ni = 0; ni < 4; ni++) acc[mi][ni] = (f32x4){0.f, 0.f, 0.f, 0.f};

  auto stage = [&](int buf, int k) {
    if (AF32) {
      gll16(Af + k, sAf + buf * 4096 + w * 512);
      gll16(Af + 8 * lda + k, sAf + buf * 4096 + w * 512 + 256);
    } else {
      gll16(As + k, &smem[buf * 4096 + w * 512]);
    }
    gll16(Bs + k, &sBb[buf * 4096 + w * 512]);
  };
  stage(0, 0);
  __syncthreads();
  int cur = 0;
  for (int k0 = 0; k0 < K; k0 += 32) {
    if (k0 + 32 < K) stage(cur ^ 1, k0 + 32);
    bf16x8 af[2], bfr[4];
    if (AF32) {
      int rk = r & 7;
#pragma unroll
      for (int mi = 0; mi < 2; mi++) {
        int row = mq + mi * 16 + r;
        const float* pa = sAf + cur * 4096 + row * 32;
        float4v lo = *(const float4v*)(pa + 4 * ((2 * g) ^ rk));
        float4v hi = *(const float4v*)(pa + 4 * ((2 * g + 1) ^ rk));
        bf16x4 l4 = cvt4(lo), h4 = cvt4(hi);
        bf16x8 a = { l4[0], l4[1], l4[2], l4[3], h4[0], h4[1], h4[2], h4[3] };
        af[mi] = a;
      }
    } else {
#pragma unroll
      for (int mi = 0; mi < 2; mi++)
        af[mi] = *(bf16x8*)&smem[cur * 4096 + (mq + mi * 16 + r) * 32 + 8 * (g ^ fsw)];
    }
#pragma unroll
    for (int ni = 0; ni < 4; ni++)
      bfr[ni] = *(bf16x8*)&sBb[cur * 4096 + (nq + ni * 16 + r) * 32 + 8 * (g ^ fsw)];
#pragma unroll
    for (int mi = 0; mi < 2; mi++)
#pragma unroll
      for (int ni = 0; ni < 4; ni++)
        acc[mi][ni] = __builtin_amdgcn_mfma_f32_16x16x32_bf16(af[mi], bfr[ni], acc[mi][ni], 0, 0, 0);
    __syncthreads();
    cur ^= 1;
  }

  if (cmode == 2) {
    // head-major: tile = 8 contiguous 4KB spans, chunk = (row&3)*2 + (col>>6).
    // acc -> LDS image [8][2048] -> wave w streams chunk w (4 x 1KB stores).
#pragma unroll
    for (int mi = 0; mi < 2; mi++)
#pragma unroll
      for (int ni = 0; ni < 4; ni++) {
        int cl = nq + ni * 16 + r;
        float bv = bias ? bias[n0 + cl] : 0.f;
        int chunkb = ((g & 3) ? 0 : 0);  // placeholder no-op
#pragma unroll
        for (int j = 0; j < 4; j++) {
          int rl = mq + mi * 16 + g * 4 + j;
          float val = (acc[mi][ni][j] + bv) * scale;
          int chunk = (rl & 3) * 2 + (cl >> 6);
          smem[chunk * 2048 + (rl >> 2) * 64 + (cl & 63)] = (bf16)val;
        }
        (void)chunkb;
      }
    __syncthreads();
    {
      int b_ = w >> 1, hl = w & 1;
      long gbase = ((long)(b_ * 16 + (n0 >> 6) + hl)) * 65536 + (long)(m0 >> 2) * 64;
#pragma unroll
      for (int it = 0; it < 4; it++) {
        bf16x8 v = *(bf16x8*)&smem[w * 2048 + it * 512 + lane * 8];
        *(bf16x8*)&((bf16*)C)[gbase + it * 512 + lane * 8] = v;
      }
    }
    return;
  }

  if (cmode == 3) {
    // acc -> LDS in vf order -> coalesced 1KB/wave stores (R15-verified map).
#pragma unroll
    for (int mi = 0; mi < 2; mi++) {
      int s32 = (mq >> 2) + mi * 4 + g;
      int gq = (s32 >> 2) & 3;
      int u = ((s32 >> 4) << 2) | (s32 & 3);
#pragma unroll
      for (int ni = 0; ni < 4; ni++) {
        int col = n0 + nq + ni * 16 + r;
        float bv = bias ? bias[col] : 0.f;
        int clbase = ((nq >> 5) + (ni >> 1)) * 2 + (ni & 1);
#pragma unroll
        for (int j = 0; j < 4; j++) {
          float val = (acc[mi][ni][j] + bv) * scale;
          smem[(j * 8 + clbase) * 512 + (gq * 16 + r) * 8 + u] = (bf16)val;
        }
      }
    }
    __syncthreads();
    int sc_ = m0 >> 7;
    int hh0 = (n0 & 511) >> 5;
    int half = n0 >> 9;
#pragma unroll
    for (int c = 0; c < 4; c++) {
      int cl = w * 4 + c;
      int b_ = cl >> 3, hl = (cl >> 1) & 3, dl = cl & 1;
      long chunk = ((long)(b_ * 16 + hh0 + hl) * 32 + sc_) * 4 + half * 2 + dl;
      bf16x8 v = *(bf16x8*)&smem[cl * 512 + lane * 8];
      *(bf16x8*)&((bf16*)C)[(chunk << 9) + lane * 8] = v;
    }
    return;
  }

#pragma unroll
  for (int mi = 0; mi < 2; mi++)
#pragma unroll
    for (int ni = 0; ni < 4; ni++) {
      int col = n0 + nq + ni * 16 + r;
      float bv = bias ? bias[col] : 0.f;
#pragma unroll
      for (int j = 0; j < 4; j++) {
        int row = m0 + mq + mi * 16 + g * 4 + j;
        float val = (acc[mi][ni][j] + bv) * scale;
        if (cmode == 1) {
          ((bf16*)C)[(long)row * ldc + col] = (bf16)val;
        } else {
          ((float*)C)[(long)row * ldc + col] = val;
        }
      }
    }
}

// out-projection (bf16 A, cmode 0)
__global__ __launch_bounds__(512) void gemm_out(
    const bf16* __restrict__ A, const bf16* __restrict__ B,
    float* __restrict__ C, const float* __restrict__ bias) {
  int nwg = gridDim.x * gridDim.y;
  int flat = blockIdx.x + gridDim.x * blockIdx.y;
  int work = xcd_swz(flat, nwg);
  int n = work % gridDim.x, m = work / gridDim.x;
  gemm_core<false>(A, 1024, B, 1024, C, 1024, bias, 1.0f, 1024, m * 128, n * 128, 0);
}

// fused q/k/v projection straight from f32 inputs (gll-DMA staged);
// q,k -> head-major via cmode2 LDS epilogue; v (z=2) -> vf (cmode 3)
__global__ __launch_bounds__(512) void gemm_proj(
    const float* __restrict__ q, const float* __restrict__ k,
    const float* __restrict__ v, const bf16* __restrict__ WT,
    const float* __restrict__ bias, bf16* __restrict__ qkout,
    bf16* __restrict__ vf) {
  int nwg = gridDim.x * gridDim.y * gridDim.z;
  int flat = blockIdx.x + gridDim.x * (blockIdx.y + gridDim.y * blockIdx.z);
  int work = xcd_swz(flat, nwg);
  int n = work % gridDim.x;
  int m = (work / gridDim.x) % gridDim.y;
  int z = work / (gridDim.x * gridDim.y);
  const float* A = (z == 0) ? q : ((z == 1) ? k : v);
  const bf16* B = WT + (long)z * 1048576;
  const float* bz = bias + z * 1024;
  void* C = (z == 2) ? (void*)vf : (void*)(qkout + (long)z * 4194304);
  float scale = (z == 0) ? 0.125f * LOG2E : 1.0f;
  gemm_core<true>(A, 1024, B, 1024, C, 1024, bz, scale, 1024, m * 128, n * 128,
                  z == 2 ? 3 : 2);
}

// ---------------- fused attention + avg_w (one launch, 256 thr) -------------
// blocks [0,1024): attn v12 (bh = bid%64, t0 = bid/64).
// blocks [1024,1536): avg_w 64x128-tile GEMM over head-major qh/kh.
// Shared 32KB LDS arena unioned across the two bodies -> 5 blocks/CU.
__global__ __launch_bounds__(256) void attn_avg(
    const bf16* __restrict__ qh, const bf16* __restrict__ kh,
    const bf16* __restrict__ vf, bf16* __restrict__ attn_b,
    float* __restrict__ out_avg, float avg_scale) {
  __shared__ __align__(16) bf16 smem[16384];  // 32 KB arena
  int tid = threadIdx.x, w = tid >> 6, lane = tid & 63, r = lane & 15, g = lane >> 4;
  int fsw = (r >> 1) & 3;

  if (blockIdx.x >= 1024) {
    // ---------- avg_w: C[bb][t][s] = avg_scale * sum_e qh[t][e] kh[s][e] ----
    bf16* sA = smem;            // [2][2048]
    bf16* sB = smem + 4096;     // [2][4096]
    int work = xcd_swz(blockIdx.x - 1024, 512);
    int n0 = (work & 7) * 128;
    int m0 = ((work >> 3) & 15) * 64;
    int bb = work >> 7;
    int mq = (w >> 1) * 32, nq = (w & 1) * 64;
    int srow = w * 16 + (lane >> 2);            // 0..63
    int scol = ((lane & 3) ^ ((srow >> 1) & 3)) * 8;
    const bf16* Asb = qh + (long)bb * 1048576 + (long)(m0 + srow) * 64 + scol;
    const bf16* Bs0 = kh + (long)bb * 1048576 + (long)(n0 + srow) * 64 + scol;
    const bf16* Bs1 = kh + (long)bb * 1048576 + (long)(n0 + srow + 64) * 64 + scol;

    f32x4 acc[2][4];
#pragma unroll
    for (int mi = 0; mi < 2; mi++)
#pragma unroll
      for (int ni = 0; ni < 4; ni++) acc[mi][ni] = (f32x4){0.f, 0.f, 0.f, 0.f};

    auto stage = [&](int buf, long off) {
      gll16(Asb + off, &sA[buf * 2048 + w * 512]);
      gll16(Bs0 + off, &sB[buf * 4096 + w * 512]);
      gll16(Bs1 + off, &sB[buf * 4096 + 2048 + w * 512]);
    };
    stage(0, 0);
    __syncthreads();
    int cur = 0;
    for (int k0 = 0; k0 < 1024; k0 += 32) {
      if (k0 + 32 < 1024) {
        int kn = k0 + 32;
        stage(cur ^ 1, ((long)(kn >> 6)) * 65536 + (kn & 63));
      }
      bf16x8 af[2], bfr[4];
#pragma unroll
      for (int mi = 0; mi < 2; mi++)
        af[mi] = *(bf16x8*)&sA[cur * 2048 + (mq + mi * 16 + r) * 32 + 8 * (g ^ fsw)];
#pragma unroll
      for (int ni = 0; ni < 4; ni++)
        bfr[ni] = *(bf16x8*)&sB[cur * 4096 + (nq + ni * 16 + r) * 32 + 8 * (g ^ fsw)];
#pragma unroll
      for (int mi = 0; mi < 2; mi++)
#pragma unroll
        for (int ni = 0; ni < 4; ni++)
          acc[mi][ni] = __builtin_amdgcn_mfma_f32_16x16x32_bf16(af[mi], bfr[ni], acc[mi][ni], 0, 0, 0);
      __syncthreads();
      cur ^= 1;
    }
#pragma unroll
    for (int mi = 0; mi < 2; mi++)
#pragma unroll
      for (int ni = 0; ni < 4; ni++) {
        int col = n0 + nq + ni * 16 + r;
#pragma unroll
        for (int j = 0; j < 4; j++) {
          int row = m0 + mq + mi * 16 + g * 4 + j;
          out_avg[(long)bb * 1048576 + (long)row * 1024 + col] = acc[mi][ni][j] * avg_scale;
        }
      }
    return;
  }

  // ---------- attn (v12): 4 waves, 16 t-rows/wave, full-S sweep ----------
  bf16* sK = smem;            // [2][4096]
  bf16* sV = smem + 8192;     // [2][4096]
  int bh = blockIdx.x & 63;
  int b = bh >> 4, h = bh & 15;
  int t0 = (blockIdx.x >> 6) * 64;
  int tw = t0 + w * 16;

  const bf16* qrow = qh + ((long)bh * 1024 + tw + r) * 64;
  bf16x8 aq0 = *(const bf16x8*)(qrow + g * 8);
  bf16x8 aq1 = *(const bf16x8*)(qrow + 32 + g * 8);

  float sp_acc = 0.f, sn_acc = 0.f;
  f32x4 o[4];
#pragma unroll
  for (int d = 0; d < 4; d++) o[d] = (f32x4){0.f, 0.f, 0.f, 0.f};

  const bf16* kbh = kh + (long)bh * 65536;
  const bf16* vbh = vf + (long)bh * 65536;

  int krow = w * 16 + (lane >> 3);
  const bf16* ksrc = kbh + (long)krow * 64 + 8 * ((lane & 7) ^ (krow & 7));
  const bf16* vsrc = vbh + w * 1024 + lane * 8;
  int c0 = 8 * (g ^ (r & 7));
  int c1 = 8 * ((g + 4) ^ (r & 7));

  auto stage = [&](int buf, int st) {
    const bf16* kp = ksrc + st * 4096;
    gll16(kp, &sK[buf * 4096 + w * 1024]);
    gll16(kp + 512, &sK[buf * 4096 + w * 1024 + 512]);
    const bf16* vp = vsrc + st * 4096;
    gll16(vp, &sV[buf * 4096 + w * 1024]);
    gll16(vp + 512, &sV[buf * 4096 + w * 1024 + 512]);
  };
  stage(0, 0);
  __syncthreads();
  int cur = 0;
#pragma unroll 1
  for (int st = 0; st < 16; st++) {
    if (st < 15) stage(cur ^ 1, st + 1);
    f32x4 sc4[4];
#pragma unroll
    for (int sf = 0; sf < 4; sf++) {
      int row = sf * 16 + r;
      bf16x8 k0 = *(const bf16x8*)&sK[cur * 4096 + row * 64 + c0];
      bf16x8 k1 = *(const bf16x8*)&sK[cur * 4096 + row * 64 + c1];
      f32x4 z = (f32x4){0.f, 0.f, 0.f, 0.f};
      z = __builtin_amdgcn_mfma_f32_16x16x32_bf16(k0, aq0, z, 0, 0, 0);
      z = __builtin_amdgcn_mfma_f32_16x16x32_bf16(k1, aq1, z, 0, 0, 0);
      sc4[sf] = z;
    }
    bf16x8 pP[2], pN[2];
#pragma unroll
    for (int sf = 0; sf < 4; sf++)
#pragma unroll
      for (int j = 0; j < 4; j++) {
        float e = __builtin_amdgcn_exp2f(sc4[sf][j]);
        sp_acc += e;
        pP[sf >> 1][(sf & 1) * 4 + j] = (bf16)e;
        float f = __builtin_amdgcn_exp2f(-sc4[sf][j]);
        sn_acc += f;
        pN[sf >> 1][(sf & 1) * 4 + j] = (bf16)f;
      }
#pragma unroll
    for (int c = 0; c < 2; c++)
#pragma unroll
      for (int dblk = 0; dblk < 4; dblk++) {
        bf16x8 vv = *(const bf16x8*)&sV[cur * 4096 + (c * 4 + dblk) * 512 + lane * 8];
        o[dblk] = __builtin_amdgcn_mfma_f32_16x16x32_bf16(
            vv, (dblk < 2) ? pP[c] : pN[c], o[dblk], 0, 0, 0);
      }
    __syncthreads();
    cur ^= 1;
  }

  sp_acc += __shfl_xor(sp_acc, 16); sp_acc += __shfl_xor(sp_acc, 32);
  sn_acc += __shfl_xor(sn_acc, 16); sn_acc += __shfl_xor(sn_acc, 32);
  float rlp = 1.f / sp_acc, rln = 1.f / sn_acc;
  long obase = ((long)(tw + r) * 4 + b) * 1024 + h * 64;
#pragma unroll
  for (int dblk = 0; dblk < 4; dblk++) {
    float rl = (dblk < 2) ? rlp : rln;
    bf16x4 ov;
#pragma unroll
    for (int j = 0; j < 4; j++) ov[j] = (bf16)(o[dblk][j] * rl);
    *(bf16x4*)&attn_b[obase + (dblk >> 1) * 32 + (dblk & 1) * 16 + g * 4] = ov;
  }
}

// ---------------- launcher ----------------
extern "C" void kernel_launch(void* const* d_in, const int* in_sizes, int n_in,
                              void* d_out, int out_size, void* d_ws, size_t ws_size,
                              hipStream_t stream) {
  (void)in_sizes; (void)n_in; (void)out_size; (void)ws_size;
  const float* query = (const float*)d_in[0];
  const float* key   = (const float*)d_in[1];
  const float* value = (const float*)d_in[2];
  const float* W     = (const float*)d_in[3];
  const float* bias  = (const float*)d_in[4];
  const float* out_w = (const float*)d_in[5];
  const float* out_b = (const float*)d_in[6];

  char* ws = (char*)d_ws;
  const long MB = 1 << 20;
  bf16* qh  = (bf16*)(ws + 0 * MB);
  bf16* kh  = (bf16*)(ws + 8 * MB);
  bf16* vf  = (bf16*)(ws + 24 * MB);
  bf16* ab  = (bf16*)(ws + 32 * MB);
  bf16* WT  = (bf16*)(ws + 40 * MB);
  bf16* owb = (bf16*)(ws + 46 * MB);
  float* out_attn = (float*)d_out;
  float* out_avg  = (float*)d_out + (size_t)4 * 1024 * 1024;

  // prep: W transpose + out_w conversion only (q/k/v consumed directly by proj)
  prep_all<<<dim3(1792), 256, 0, stream>>>(W, out_w, WT, owb);

  // projections straight from f32 inputs: q,k -> head-major; v -> vf fragment
  gemm_proj<<<dim3(8, 32, 3), 512, 0, stream>>>(query, key, value, WT, bias, qh, vf);

  // fused: attention (blocks 0..1023) + avg_w GEMM (blocks 1024..1535)
  attn_avg<<<dim3(1536), 256, 0, stream>>>(qh, kh, vf, ab, out_avg,
                                           1.f / (16.f * LOG2E));

  // out projection: C = attn @ out_w^T + out_b
  gemm_out<<<dim3(8, 32), 512, 0, stream>>>(ab, owb, out_attn, out_b);
}

// Round 21
// 104.672 us; speedup vs baseline: 1.0028x; 1.0028x over previous
//
#include <hip/hip_runtime.h>
#include <hip/hip_bf16.h>

// Problem constants: E=1024, H=16, HD=64, T=1024, B=4, S=1024.
// d_out: attn(T,B,E) f32 [4M floats] then avg_w(B,T,S) f32 [4M floats].
// ws layout (bytes): qh 0..8M (head-major [bh][t][64], q pre-scaled 0.125*log2e),
//   kh 8..16M, vf 24..32M (frag-swizzled V, proj cmode3 LDS-coalesced epilogue),
//   ab 32..40M, WT 40..46M, owb 46..48M.
// q/k/v f32 inputs consumed DIRECTLY by gemm_proj via global_load_lds into f32
// LDS tiles (chunk-XOR swizzle c^=row&7; conversion at fragment-read).
// avg_w computed inside the attn launch (blocks >= 1024) for overlap.

typedef __bf16 bf16;
typedef float f32x4 __attribute__((ext_vector_type(4)));
typedef float float4v __attribute__((ext_vector_type(4)));
typedef bf16 bf16x8 __attribute__((ext_vector_type(8)));
typedef bf16 bf16x4 __attribute__((ext_vector_type(4)));

#define LOG2E 1.4426950408889634f

// async global->LDS, 16B/lane; dst base wave-uniform (HW adds lane*16).
__device__ __forceinline__ void gll16(const void* g, void* l) {
  __builtin_amdgcn_global_load_lds(
      (const __attribute__((address_space(1))) void*)g,
      (__attribute__((address_space(3))) void*)l, 16, 0, 0);
}

// XCD-chunked swizzle: consecutive works (sharing an A-panel) land on one XCD.
__device__ __forceinline__ int xcd_swz(int flat, int nwg) {
  int q = nwg >> 3;
  return (flat & 7) * q + (flat >> 3);
}

__device__ __forceinline__ bf16x4 cvt4(float4v v) {
  bf16x4 b = { (bf16)v.x, (bf16)v.y, (bf16)v.z, (bf16)v.w };
  return b;
}

// ---------------- prep kernel (W transpose + out_w conv only) ----------------
__global__ __launch_bounds__(256) void prep_all(
    const float* __restrict__ W, const float* __restrict__ out_w,
    bf16* __restrict__ WT, bf16* __restrict__ owb) {
  __shared__ bf16 tile[64][72];
  int bid = blockIdx.x;
  if (bid >= 768) {  // out_w conversion: 1024 blocks
    int i = ((bid - 768) * 256 + (int)threadIdx.x) * 4;
    float4v v = *(const float4v*)(out_w + i);
    *(bf16x4*)&owb[i] = cvt4(v);
    return;
  }
  // W transpose: dst[sec][j][i] = (bf16) src[sec*1024 + i][j]
  int sec = bid >> 8, bx = bid & 15, by = (bid >> 4) & 15;
  int i0 = by * 64, j0 = bx * 64;
  const float* s = W + (long)sec * 1048576;
  bf16* d = WT + (long)sec * 1048576;
  int t = threadIdx.x;
#pragma unroll
  for (int p = 0; p < 4; p++) {
    int ri = (t >> 4) + p * 16, cj = (t & 15) * 4;
    float4v vv = *(const float4v*)(s + (long)(i0 + ri) * 1024 + j0 + cj);
    *(bf16x4*)&tile[ri][cj] = cvt4(vv);
  }
  __syncthreads();
#pragma unroll
  for (int p = 0; p < 4; p++) {
    int rj = (t >> 4) + p * 16, ci = (t & 15) * 4;
    bf16x4 bv = { tile[ci][rj], tile[ci + 1][rj], tile[ci + 2][rj], tile[ci + 3][rj] };
    *(bf16x4*)&d[(long)(j0 + rj) * 1024 + i0 + ci] = bv;
  }
}

// ---------------- unified NT GEMM core (512 thr, 8 waves, 128x128) ----------
// R11-best loop: dbuf, stage(next) BEFORE compute(cur), ONE __syncthreads per
// k-step; all staging via global_load_lds. AF32: A f32 staged into f32 LDS
// tiles with CHUNK-XOR swizzle (float4-chunk c stored at c^(row&7); read at
// (2g)^(r&7), (2g+1)^(r&7)) -> 8 slots x 8 lanes, conflict-free; converted
// f32->bf16 at fragment read.
// cmode: 0 f32 std, 1 bf16 std, 2 bf16 head-major via PADDED-LDS epilogue
// ([8][32][80] image: write banks (8g + r/2)%32 = all 32; read 8 lanes/group;
// global stores coalesced 1KB/wave), 3 vf fragment (LDS epi).
template <bool AF32>
__device__ __forceinline__ void gemm_core(
    const void* __restrict__ Av, long lda,
    const bf16* __restrict__ B, long ldb,
    void* __restrict__ C, long ldc,
    const float* __restrict__ bias, float scale, int K,
    int m0, int n0, int cmode) {
  __shared__ bf16 smem[AF32 ? 24576 : 16384];
  float* sAf = (float*)smem;                       // AF32: [2][4096] f32
  bf16* sBb = smem + (AF32 ? 16384 : 8192);        // [2][4096] bf16
  int t = threadIdx.x;
  int w = t >> 6, lane = t & 63, r = lane & 15, g = lane >> 4;
  int mq = (w >> 1) * 32, nq = (w & 1) * 64;
  int srow = w * 16 + (lane >> 2);
  int scol = ((lane & 3) ^ ((srow >> 1) & 3)) * 8;
  int fsw = (r >> 1) & 3;
  const bf16* Bs = B + (long)(n0 + srow) * ldb + scol;
  const bf16* As = (const bf16*)Av + (long)(m0 + srow) * lda + scol;  // !AF32
  // AF32 staging: lane l stages float4-chunk (l&7) of row w*16+(l>>3) (+8 on
  // 2nd gll); the chunk LANDING at position l&7 is logical chunk (l&7)^(l>>3).
  int aro = lane >> 3;
  int acolf = 4 * ((lane & 7) ^ aro);
  const float* Af = (const float*)Av + (long)(m0 + w * 16 + aro) * lda + acolf;

  f32x4 acc[2][4];
#pragma unroll
  for (int mi = 0; mi < 2; mi++)
#pragma unroll
    for (int ni = 0; ni < 4; ni++) acc[mi][ni] = (f32x4){0.f, 0.f, 0.f, 0.f};

  auto stage = [&](int buf, int k) {
    if (AF32) {
      gll16(Af + k, sAf + buf * 4096 + w * 512);
      gll16(Af + 8 * lda + k, sAf + buf * 4096 + w * 512 + 256);
    } else {
      gll16(As + k, &smem[buf * 4096 + w * 512]);
    }
    gll16(Bs + k, &sBb[buf * 4096 + w * 512]);
  };
  stage(0, 0);
  __syncthreads();
  int cur = 0;
  for (int k0 = 0; k0 < K; k0 += 32) {
    if (k0 + 32 < K) stage(cur ^ 1, k0 + 32);
    bf16x8 af[2], bfr[4];
    if (AF32) {
      int rk = r & 7;
#pragma unroll
      for (int mi = 0; mi < 2; mi++) {
        int row = mq + mi * 16 + r;
        const float* pa = sAf + cur * 4096 + row * 32;
        float4v lo = *(const float4v*)(pa + 4 * ((2 * g) ^ rk));
        float4v hi = *(const float4v*)(pa + 4 * ((2 * g + 1) ^ rk));
        bf16x4 l4 = cvt4(lo), h4 = cvt4(hi);
        bf16x8 a = { l4[0], l4[1], l4[2], l4[3], h4[0], h4[1], h4[2], h4[3] };
        af[mi] = a;
      }
    } else {
#pragma unroll
      for (int mi = 0; mi < 2; mi++)
        af[mi] = *(bf16x8*)&smem[cur * 4096 + (mq + mi * 16 + r) * 32 + 8 * (g ^ fsw)];
    }
#pragma unroll
    for (int ni = 0; ni < 4; ni++)
      bfr[ni] = *(bf16x8*)&sBb[cur * 4096 + (nq + ni * 16 + r) * 32 + 8 * (g ^ fsw)];
#pragma unroll
    for (int mi = 0; mi < 2; mi++)
#pragma unroll
      for (int ni = 0; ni < 4; ni++)
        acc[mi][ni] = __builtin_amdgcn_mfma_f32_16x16x32_bf16(af[mi], bfr[ni], acc[mi][ni], 0, 0, 0);
    __syncthreads();
    cur ^= 1;
  }

  if (cmode == 2) {
    // head-major: tile = 8 contiguous 4KB spans, chunk = (row&3)*2 + (col>>6).
    // PADDED image [8][32][80] (40KB): write addr = chunk*2560 + tl*80 + dd,
    // banks (8g + r/2)%32 all-distinct; read at stride 80 even-distributed.
#pragma unroll
    for (int mi = 0; mi < 2; mi++) {
      int tl = (mq >> 2) + mi * 4 + g;
#pragma unroll
      for (int ni = 0; ni < 4; ni++) {
        int cl = nq + ni * 16 + r;
        float bv = bias ? bias[n0 + cl] : 0.f;
        int chunkb = (nq >> 6) * 2560 + tl * 80 + ni * 16 + r;  // + j*2*2560
#pragma unroll
        for (int j = 0; j < 4; j++) {
          float val = (acc[mi][ni][j] + bv) * scale;
          smem[j * 5120 + chunkb] = (bf16)val;
        }
      }
    }
    __syncthreads();
    {
      int b_ = w >> 1, hl = w & 1;
      long gbase = ((long)(b_ * 16 + (n0 >> 6) + hl)) * 65536 + (long)(m0 >> 2) * 64;
#pragma unroll
      for (int it = 0; it < 4; it++) {
        bf16x8 v = *(bf16x8*)&smem[w * 2560 + (it * 8 + (lane >> 3)) * 80 + (lane & 7) * 8];
        *(bf16x8*)&((bf16*)C)[gbase + it * 512 + lane * 8] = v;
      }
    }
    return;
  }

  if (cmode == 3) {
    // acc -> LDS in vf order -> coalesced 1KB/wave stores (R15-verified map).
#pragma unroll
    for (int mi = 0; mi < 2; mi++) {
      int s32 = (mq >> 2) + mi * 4 + g;
      int gq = (s32 >> 2) & 3;
      int u = ((s32 >> 4) << 2) | (s32 & 3);
#pragma unroll
      for (int ni = 0; ni < 4; ni++) {
        int col = n0 + nq + ni * 16 + r;
        float bv = bias ? bias[col] : 0.f;
        int clbase = ((nq >> 5) + (ni >> 1)) * 2 + (ni & 1);
#pragma unroll
        for (int j = 0; j < 4; j++) {
          float val = (acc[mi][ni][j] + bv) * scale;
          smem[(j * 8 + clbase) * 512 + (gq * 16 + r) * 8 + u] = (bf16)val;
        }
      }
    }
    __syncthreads();
    int sc_ = m0 >> 7;
    int hh0 = (n0 & 511) >> 5;
    int half = n0 >> 9;
#pragma unroll
    for (int c = 0; c < 4; c++) {
      int cl = w * 4 + c;
      int b_ = cl >> 3, hl = (cl >> 1) & 3, dl = cl & 1;
      long chunk = ((long)(b_ * 16 + hh0 + hl) * 32 + sc_) * 4 + half * 2 + dl;
      bf16x8 v = *(bf16x8*)&smem[cl * 512 + lane * 8];
      *(bf16x8*)&((bf16*)C)[(chunk << 9) + lane * 8] = v;
    }
    return;
  }

#pragma unroll
  for (int mi = 0; mi < 2; mi++)
#pragma unroll
    for (int ni = 0; ni < 4; ni++) {
      int col = n0 + nq + ni * 16 + r;
      float bv = bias ? bias[col] : 0.f;
#pragma unroll
      for (int j = 0; j < 4; j++) {
        int row = m0 + mq + mi * 16 + g * 4 + j;
        float val = (acc[mi][ni][j] + bv) * scale;
        if (cmode == 1) {
          ((bf16*)C)[(long)row * ldc + col] = (bf16)val;
        } else {
          ((float*)C)[(long)row * ldc + col] = val;
        }
      }
    }
}

// out-projection (bf16 A, cmode 0)
__global__ __launch_bounds__(512) void gemm_out(
    const bf16* __restrict__ A, const bf16* __restrict__ B,
    float* __restrict__ C, const float* __restrict__ bias) {
  int nwg = gridDim.x * gridDim.y;
  int flat = blockIdx.x + gridDim.x * blockIdx.y;
  int work = xcd_swz(flat, nwg);
  int n = work % gridDim.x, m = work / gridDim.x;
  gemm_core<false>(A, 1024, B, 1024, C, 1024, bias, 1.0f, 1024, m * 128, n * 128, 0);
}

// fused q/k/v projection straight from f32 inputs (gll-DMA staged);
// q,k -> head-major via cmode2 padded-LDS epilogue; v (z=2) -> vf (cmode 3)
__global__ __launch_bounds__(512) void gemm_proj(
    const float* __restrict__ q, const float* __restrict__ k,
    const float* __restrict__ v, const bf16* __restrict__ WT,
    const float* __restrict__ bias, bf16* __restrict__ qkout,
    bf16* __restrict__ vf) {
  int nwg = gridDim.x * gridDim.y * gridDim.z;
  int flat = blockIdx.x + gridDim.x * (blockIdx.y + gridDim.y * blockIdx.z);
  int work = xcd_swz(flat, nwg);
  int n = work % gridDim.x;
  int m = (work / gridDim.x) % gridDim.y;
  int z = work / (gridDim.x * gridDim.y);
  const float* A = (z == 0) ? q : ((z == 1) ? k : v);
  const bf16* B = WT + (long)z * 1048576;
  const float* bz = bias + z * 1024;
  void* C = (z == 2) ? (void*)vf : (void*)(qkout + (long)z * 4194304);
  float scale = (z == 0) ? 0.125f * LOG2E : 1.0f;
  gemm_core<true>(A, 1024, B, 1024, C, 1024, bz, scale, 1024, m * 128, n * 128,
                  z == 2 ? 3 : 2);
}

// ---------------- fused attention + avg_w (one launch, 256 thr) -------------
// blocks [0,1024): attn v12 (bh = bid%64, t0 = bid/64).
// blocks [1024,1536): avg_w 64x128-tile GEMM over head-major qh/kh.
// Shared 32KB LDS arena unioned across the two bodies -> 5 blocks/CU.
__global__ __launch_bounds__(256) void attn_avg(
    const bf16* __restrict__ qh, const bf16* __restrict__ kh,
    const bf16* __restrict__ vf, bf16* __restrict__ attn_b,
    float* __restrict__ out_avg, float avg_scale) {
  __shared__ __align__(16) bf16 smem[16384];  // 32 KB arena
  int tid = threadIdx.x, w = tid >> 6, lane = tid & 63, r = lane & 15, g = lane >> 4;
  int fsw = (r >> 1) & 3;

  if (blockIdx.x >= 1024) {
    // ---------- avg_w: C[bb][t][s] = avg_scale * sum_e qh[t][e] kh[s][e] ----
    bf16* sA = smem;            // [2][2048]
    bf16* sB = smem + 4096;     // [2][4096]
    int work = xcd_swz(blockIdx.x - 1024, 512);
    int n0 = (work & 7) * 128;
    int m0 = ((work >> 3) & 15) * 64;
    int bb = work >> 7;
    int mq = (w >> 1) * 32, nq = (w & 1) * 64;
    int srow = w * 16 + (lane >> 2);            // 0..63
    int scol = ((lane & 3) ^ ((srow >> 1) & 3)) * 8;
    const bf16* Asb = qh + (long)bb * 1048576 + (long)(m0 + srow) * 64 + scol;
    const bf16* Bs0 = kh + (long)bb * 1048576 + (long)(n0 + srow) * 64 + scol;
    const bf16* Bs1 = kh + (long)bb * 1048576 + (long)(n0 + srow + 64) * 64 + scol;

    f32x4 acc[2][4];
#pragma unroll
    for (int mi = 0; mi < 2; mi++)
#pragma unroll
      for (int ni = 0; ni < 4; ni++) acc[mi][ni] = (f32x4){0.f, 0.f, 0.f, 0.f};

    auto stage = [&](int buf, long off) {
      gll16(Asb + off, &sA[buf * 2048 + w * 512]);
      gll16(Bs0 + off, &sB[buf * 4096 + w * 512]);
      gll16(Bs1 + off, &sB[buf * 4096 + 2048 + w * 512]);
    };
    stage(0, 0);
    __syncthreads();
    int cur = 0;
    for (int k0 = 0; k0 < 1024; k0 += 32) {
      if (k0 + 32 < 1024) {
        int kn = k0 + 32;
        stage(cur ^ 1, ((long)(kn >> 6)) * 65536 + (kn & 63));
      }
      bf16x8 af[2], bfr[4];
#pragma unroll
      for (int mi = 0; mi < 2; mi++)
        af[mi] = *(bf16x8*)&sA[cur * 2048 + (mq + mi * 16 + r) * 32 + 8 * (g ^ fsw)];
#pragma unroll
      for (int ni = 0; ni < 4; ni++)
        bfr[ni] = *(bf16x8*)&sB[cur * 4096 + (nq + ni * 16 + r) * 32 + 8 * (g ^ fsw)];
#pragma unroll
      for (int mi = 0; mi < 2; mi++)
#pragma unroll
        for (int ni = 0; ni < 4; ni++)
          acc[mi][ni] = __builtin_amdgcn_mfma_f32_16x16x32_bf16(af[mi], bfr[ni], acc[mi][ni], 0, 0, 0);
      __syncthreads();
      cur ^= 1;
    }
#pragma unroll
    for (int mi = 0; mi < 2; mi++)
#pragma unroll
      for (int ni = 0; ni < 4; ni++) {
        int col = n0 + nq + ni * 16 + r;
#pragma unroll
        for (int j = 0; j < 4; j++) {
          int row = m0 + mq + mi * 16 + g * 4 + j;
          out_avg[(long)bb * 1048576 + (long)row * 1024 + col] = acc[mi][ni][j] * avg_scale;
        }
      }
    return;
  }

  // ---------- attn (v12): 4 waves, 16 t-rows/wave, full-S sweep ----------
  bf16* sK = smem;            // [2][4096]
  bf16* sV = smem + 8192;     // [2][4096]
  int bh = blockIdx.x & 63;
  int b = bh >> 4, h = bh & 15;
  int t0 = (blockIdx.x >> 6) * 64;
  int tw = t0 + w * 16;

  const bf16* qrow = qh + ((long)bh * 1024 + tw + r) * 64;
  bf16x8 aq0 = *(const bf16x8*)(qrow + g * 8);
  bf16x8 aq1 = *(const bf16x8*)(qrow + 32 + g * 8);

  float sp_acc = 0.f, sn_acc = 0.f;
  f32x4 o[4];
#pragma unroll
  for (int d = 0; d < 4; d++) o[d] = (f32x4){0.f, 0.f, 0.f, 0.f};

  const bf16* kbh = kh + (long)bh * 65536;
  const bf16* vbh = vf + (long)bh * 65536;

  int krow = w * 16 + (lane >> 3);
  const bf16* ksrc = kbh + (long)krow * 64 + 8 * ((lane & 7) ^ (krow & 7));
  const bf16* vsrc = vbh + w * 1024 + lane * 8;
  int c0 = 8 * (g ^ (r & 7));
  int c1 = 8 * ((g + 4) ^ (r & 7));

  auto stage = [&](int buf, int st) {
    const bf16* kp = ksrc + st * 4096;
    gll16(kp, &sK[buf * 4096 + w * 1024]);
    gll16(kp + 512, &sK[buf * 4096 + w * 1024 + 512]);
    const bf16* vp = vsrc + st * 4096;
    gll16(vp, &sV[buf * 4096 + w * 1024]);
    gll16(vp + 512, &sV[buf * 4096 + w * 1024 + 512]);
  };
  stage(0, 0);
  __syncthreads();
  int cur = 0;
#pragma unroll 1
  for (int st = 0; st < 16; st++) {
    if (st < 15) stage(cur ^ 1, st + 1);
    f32x4 sc4[4];
#pragma unroll
    for (int sf = 0; sf < 4; sf++) {
      int row = sf * 16 + r;
      bf16x8 k0 = *(const bf16x8*)&sK[cur * 4096 + row * 64 + c0];
      bf16x8 k1 = *(const bf16x8*)&sK[cur * 4096 + row * 64 + c1];
      f32x4 z = (f32x4){0.f, 0.f, 0.f, 0.f};
      z = __builtin_amdgcn_mfma_f32_16x16x32_bf16(k0, aq0, z, 0, 0, 0);
      z = __builtin_amdgcn_mfma_f32_16x16x32_bf16(k1, aq1, z, 0, 0, 0);
      sc4[sf] = z;
    }
    bf16x8 pP[2], pN[2];
#pragma unroll
    for (int sf = 0; sf < 4; sf++)
#pragma unroll
      for (int j = 0; j < 4; j++) {
        float e = __builtin_amdgcn_exp2f(sc4[sf][j]);
        sp_acc += e;
        pP[sf >> 1][(sf & 1) * 4 + j] = (bf16)e;
        float f = __builtin_amdgcn_exp2f(-sc4[sf][j]);
        sn_acc += f;
        pN[sf >> 1][(sf & 1) * 4 + j] = (bf16)f;
      }
#pragma unroll
    for (int c = 0; c < 2; c++)
#pragma unroll
      for (int dblk = 0; dblk < 4; dblk++) {
        bf16x8 vv = *(const bf16x8*)&sV[cur * 4096 + (c * 4 + dblk) * 512 + lane * 8];
        o[dblk] = __builtin_amdgcn_mfma_f32_16x16x32_bf16(
            vv, (dblk < 2) ? pP[c] : pN[c], o[dblk], 0, 0, 0);
      }
    __syncthreads();
    cur ^= 1;
  }

  sp_acc += __shfl_xor(sp_acc, 16); sp_acc += __shfl_xor(sp_acc, 32);
  sn_acc += __shfl_xor(sn_acc, 16); sn_acc += __shfl_xor(sn_acc, 32);
  float rlp = 1.f / sp_acc, rln = 1.f / sn_acc;
  long obase = ((long)(tw + r) * 4 + b) * 1024 + h * 64;
#pragma unroll
  for (int dblk = 0; dblk < 4; dblk++) {
    float rl = (dblk < 2) ? rlp : rln;
    bf16x4 ov;
#pragma unroll
    for (int j = 0; j < 4; j++) ov[j] = (bf16)(o[dblk][j] * rl);
    *(bf16x4*)&attn_b[obase + (dblk >> 1) * 32 + (dblk & 1) * 16 + g * 4] = ov;
  }
}

// ---------------- launcher ----------------
extern "C" void kernel_launch(void* const* d_in, const int* in_sizes, int n_in,
                              void* d_out, int out_size, void* d_ws, size_t ws_size,
                              hipStream_t stream) {
  (void)in_sizes; (void)n_in; (void)out_size; (void)ws_size;
  const float* query = (const float*)d_in[0];
  const float* key   = (const float*)d_in[1];
  const float* value = (const float*)d_in[2];
  const float* W     = (const float*)d_in[3];
  const float* bias  = (const float*)d_in[4];
  const float* out_w = (const float*)d_in[5];
  const float* out_b = (const float*)d_in[6];

  char* ws = (char*)d_ws;
  const long MB = 1 << 20;
  bf16* qh  = (bf16*)(ws + 0 * MB);
  bf16* kh  = (bf16*)(ws + 8 * MB);
  bf16* vf  = (bf16*)(ws + 24 * MB);
  bf16* ab  = (bf16*)(ws + 32 * MB);
  bf16* WT  = (bf16*)(ws + 40 * MB);
  bf16* owb = (bf16*)(ws + 46 * MB);
  float* out_attn = (float*)d_out;
  float* out_avg  = (float*)d_out + (size_t)4 * 1024 * 1024;

  // prep: W transpose + out_w conversion only (q/k/v consumed directly by proj)
  prep_all<<<dim3(1792), 256, 0, stream>>>(W, out_w, WT, owb);

  // projections straight from f32 inputs: q,k -> head-major; v -> vf fragment
  gemm_proj<<<dim3(8, 32, 3), 512, 0, stream>>>(query, key, value, WT, bias, qh, vf);

  // fused: attention (blocks 0..1023) + avg_w GEMM (blocks 1024..1535)
  attn_avg<<<dim3(1536), 256, 0, stream>>>(qh, kh, vf, ab, out_avg,
                                           1.f / (16.f * LOG2E));

  // out projection: C = attn @ out_w^T + out_b
  gemm_out<<<dim3(8, 32), 512, 0, stream>>>(ab, owb, out_attn, out_b);
}

// Round 23
// 101.846 us; speedup vs baseline: 1.0306x; 1.0277x over previous
//
#include <hip/hip_runtime.h>
#include <hip/hip_bf16.h>

// Problem constants: E=1024, H=16, HD=64, T=1024, B=4, S=1024.
// d_out: attn(T,B,E) f32 [4M floats] then avg_w(B,T,S) f32 [4M floats].
// ws layout (bytes): qh 0..8M (head-major [bh][t][64], q pre-scaled 0.125*log2e),
//   kh 8..16M, vf 24..32M (frag-swizzled V, proj cmode3 LDS-coalesced epilogue),
//   ab 32..40M, WT 40..46M, owb 46..48M.
// q/k/v f32 inputs consumed DIRECTLY by gemm_proj via global_load_lds into f32
// LDS tiles (chunk-XOR swizzle c^=row&7; conversion at fragment-read).
// avg_w computed inside the attn launch: 768 blocks x 512 thr = exactly
// 3 blocks/CU x 256 CU -> single dispatch wave, no tail.
// attn blocks [0,512): 8 waves x 16 t-rows. avg blocks [512,768): 128x128
// tiles, 8(n) x 8(m) x 4(b) = 256 blocks (R22 crash: had 512 -> bb OOB).

typedef __bf16 bf16;
typedef float f32x4 __attribute__((ext_vector_type(4)));
typedef float float4v __attribute__((ext_vector_type(4)));
typedef bf16 bf16x8 __attribute__((ext_vector_type(8)));
typedef bf16 bf16x4 __attribute__((ext_vector_type(4)));

#define LOG2E 1.4426950408889634f

// async global->LDS, 16B/lane; dst base wave-uniform (HW adds lane*16).
__device__ __forceinline__ void gll16(const void* g, void* l) {
  __builtin_amdgcn_global_load_lds(
      (const __attribute__((address_space(1))) void*)g,
      (__attribute__((address_space(3))) void*)l, 16, 0, 0);
}

// XCD-chunked swizzle: consecutive works (sharing an A-panel) land on one XCD.
__device__ __forceinline__ int xcd_swz(int flat, int nwg) {
  int q = nwg >> 3;
  return (flat & 7) * q + (flat >> 3);
}

__device__ __forceinline__ bf16x4 cvt4(float4v v) {
  bf16x4 b = { (bf16)v.x, (bf16)v.y, (bf16)v.z, (bf16)v.w };
  return b;
}

// ---------------- prep kernel (W transpose + out_w conv only) ----------------
__global__ __launch_bounds__(256) void prep_all(
    const float* __restrict__ W, const float* __restrict__ out_w,
    bf16* __restrict__ WT, bf16* __restrict__ owb) {
  __shared__ bf16 tile[64][72];
  int bid = blockIdx.x;
  if (bid >= 768) {  // out_w conversion: 1024 blocks
    int i = ((bid - 768) * 256 + (int)threadIdx.x) * 4;
    float4v v = *(const float4v*)(out_w + i);
    *(bf16x4*)&owb[i] = cvt4(v);
    return;
  }
  // W transpose: dst[sec][j][i] = (bf16) src[sec*1024 + i][j]
  int sec = bid >> 8, bx = bid & 15, by = (bid >> 4) & 15;
  int i0 = by * 64, j0 = bx * 64;
  const float* s = W + (long)sec * 1048576;
  bf16* d = WT + (long)sec * 1048576;
  int t = threadIdx.x;
#pragma unroll
  for (int p = 0; p < 4; p++) {
    int ri = (t >> 4) + p * 16, cj = (t & 15) * 4;
    float4v vv = *(const float4v*)(s + (long)(i0 + ri) * 1024 + j0 + cj);
    *(bf16x4*)&tile[ri][cj] = cvt4(vv);
  }
  __syncthreads();
#pragma unroll
  for (int p = 0; p < 4; p++) {
    int rj = (t >> 4) + p * 16, ci = (t & 15) * 4;
    bf16x4 bv = { tile[ci][rj], tile[ci + 1][rj], tile[ci + 2][rj], tile[ci + 3][rj] };
    *(bf16x4*)&d[(long)(j0 + rj) * 1024 + i0 + ci] = bv;
  }
}

// ---------------- unified NT GEMM core (512 thr, 8 waves, 128x128) ----------
// R11-best loop: dbuf, stage(next) BEFORE compute(cur), ONE __syncthreads per
// k-step; all staging via global_load_lds. AF32: A f32 staged into f32 LDS
// tiles with CHUNK-XOR swizzle (float4-chunk c stored at c^(row&7); read at
// (2g)^(r&7), (2g+1)^(r&7)); converted f32->bf16 at fragment read.
// cmode: 0 f32 std, 1 bf16 std, 2 bf16 head-major via PADDED-LDS epilogue,
// 3 vf fragment (LDS epi).
template <bool AF32>
__device__ __forceinline__ void gemm_core(
    const void* __restrict__ Av, long lda,
    const bf16* __restrict__ B, long ldb,
    void* __restrict__ C, long ldc,
    const float* __restrict__ bias, float scale, int K,
    int m0, int n0, int cmode) {
  __shared__ bf16 smem[AF32 ? 24576 : 16384];
  float* sAf = (float*)smem;                       // AF32: [2][4096] f32
  bf16* sBb = smem + (AF32 ? 16384 : 8192);        // [2][4096] bf16
  int t = threadIdx.x;
  int w = t >> 6, lane = t & 63, r = lane & 15, g = lane >> 4;
  int mq = (w >> 1) * 32, nq = (w & 1) * 64;
  int srow = w * 16 + (lane >> 2);
  int scol = ((lane & 3) ^ ((srow >> 1) & 3)) * 8;
  int fsw = (r >> 1) & 3;
  const bf16* Bs = B + (long)(n0 + srow) * ldb + scol;
  const bf16* As = (const bf16*)Av + (long)(m0 + srow) * lda + scol;  // !AF32
  int aro = lane >> 3;
  int acolf = 4 * ((lane & 7) ^ aro);
  const float* Af = (const float*)Av + (long)(m0 + w * 16 + aro) * lda + acolf;

  f32x4 acc[2][4];
#pragma unroll
  for (int mi = 0; mi < 2; mi++)
#pragma unroll
    for (int ni = 0; ni < 4; ni++) acc[mi][ni] = (f32x4){0.f, 0.f, 0.f, 0.f};

  auto stage = [&](int buf, int k) {
    if (AF32) {
      gll16(Af + k, sAf + buf * 4096 + w * 512);
      gll16(Af + 8 * lda + k, sAf + buf * 4096 + w * 512 + 256);
    } else {
      gll16(As + k, &smem[buf * 4096 + w * 512]);
    }
    gll16(Bs + k, &sBb[buf * 4096 + w * 512]);
  };
  stage(0, 0);
  __syncthreads();
  int cur = 0;
  for (int k0 = 0; k0 < K; k0 += 32) {
    if (k0 + 32 < K) stage(cur ^ 1, k0 + 32);
    bf16x8 af[2], bfr[4];
    if (AF32) {
      int rk = r & 7;
#pragma unroll
      for (int mi = 0; mi < 2; mi++) {
        int row = mq + mi * 16 + r;
        const float* pa = sAf + cur * 4096 + row * 32;
        float4v lo = *(const float4v*)(pa + 4 * ((2 * g) ^ rk));
        float4v hi = *(const float4v*)(pa + 4 * ((2 * g + 1) ^ rk));
        bf16x4 l4 = cvt4(lo), h4 = cvt4(hi);
        bf16x8 a = { l4[0], l4[1], l4[2], l4[3], h4[0], h4[1], h4[2], h4[3] };
        af[mi] = a;
      }
    } else {
#pragma unroll
      for (int mi = 0; mi < 2; mi++)
        af[mi] = *(bf16x8*)&smem[cur * 4096 + (mq + mi * 16 + r) * 32 + 8 * (g ^ fsw)];
    }
#pragma unroll
    for (int ni = 0; ni < 4; ni++)
      bfr[ni] = *(bf16x8*)&sBb[cur * 4096 + (nq + ni * 16 + r) * 32 + 8 * (g ^ fsw)];
#pragma unroll
    for (int mi = 0; mi < 2; mi++)
#pragma unroll
      for (int ni = 0; ni < 4; ni++)
        acc[mi][ni] = __builtin_amdgcn_mfma_f32_16x16x32_bf16(af[mi], bfr[ni], acc[mi][ni], 0, 0, 0);
    __syncthreads();
    cur ^= 1;
  }

  if (cmode == 2) {
    // head-major: PADDED image [8][32][80]; coalesced 1KB/wave global stores.
#pragma unroll
    for (int mi = 0; mi < 2; mi++) {
      int tl = (mq >> 2) + mi * 4 + g;
#pragma unroll
      for (int ni = 0; ni < 4; ni++) {
        int cl = nq + ni * 16 + r;
        float bv = bias ? bias[n0 + cl] : 0.f;
        int chunkb = (nq >> 6) * 2560 + tl * 80 + ni * 16 + r;
#pragma unroll
        for (int j = 0; j < 4; j++) {
          float val = (acc[mi][ni][j] + bv) * scale;
          smem[j * 5120 + chunkb] = (bf16)val;
        }
      }
    }
    __syncthreads();
    {
      int b_ = w >> 1, hl = w & 1;
      long gbase = ((long)(b_ * 16 + (n0 >> 6) + hl)) * 65536 + (long)(m0 >> 2) * 64;
#pragma unroll
      for (int it = 0; it < 4; it++) {
        bf16x8 v = *(bf16x8*)&smem[w * 2560 + (it * 8 + (lane >> 3)) * 80 + (lane & 7) * 8];
        *(bf16x8*)&((bf16*)C)[gbase + it * 512 + lane * 8] = v;
      }
    }
    return;
  }

  if (cmode == 3) {
    // acc -> LDS in vf order -> coalesced 1KB/wave stores (R15-verified map).
#pragma unroll
    for (int mi = 0; mi < 2; mi++) {
      int s32 = (mq >> 2) + mi * 4 + g;
      int gq = (s32 >> 2) & 3;
      int u = ((s32 >> 4) << 2) | (s32 & 3);
#pragma unroll
      for (int ni = 0; ni < 4; ni++) {
        int col = n0 + nq + ni * 16 + r;
        float bv = bias ? bias[col] : 0.f;
        int clbase = ((nq >> 5) + (ni >> 1)) * 2 + (ni & 1);
#pragma unroll
        for (int j = 0; j < 4; j++) {
          float val = (acc[mi][ni][j] + bv) * scale;
          smem[(j * 8 + clbase) * 512 + (gq * 16 + r) * 8 + u] = (bf16)val;
        }
      }
    }
    __syncthreads();
    int sc_ = m0 >> 7;
    int hh0 = (n0 & 511) >> 5;
    int half = n0 >> 9;
#pragma unroll
    for (int c = 0; c < 4; c++) {
      int cl = w * 4 + c;
      int b_ = cl >> 3, hl = (cl >> 1) & 3, dl = cl & 1;
      long chunk = ((long)(b_ * 16 + hh0 + hl) * 32 + sc_) * 4 + half * 2 + dl;
      bf16x8 v = *(bf16x8*)&smem[cl * 512 + lane * 8];
      *(bf16x8*)&((bf16*)C)[(chunk << 9) + lane * 8] = v;
    }
    return;
  }

#pragma unroll
  for (int mi = 0; mi < 2; mi++)
#pragma unroll
    for (int ni = 0; ni < 4; ni++) {
      int col = n0 + nq + ni * 16 + r;
      float bv = bias ? bias[col] : 0.f;
#pragma unroll
      for (int j = 0; j < 4; j++) {
        int row = m0 + mq + mi * 16 + g * 4 + j;
        float val = (acc[mi][ni][j] + bv) * scale;
        if (cmode == 1) {
          ((bf16*)C)[(long)row * ldc + col] = (bf16)val;
        } else {
          ((float*)C)[(long)row * ldc + col] = val;
        }
      }
    }
}

// out-projection (bf16 A, cmode 0)
__global__ __launch_bounds__(512) void gemm_out(
    const bf16* __restrict__ A, const bf16* __restrict__ B,
    float* __restrict__ C, const float* __restrict__ bias) {
  int nwg = gridDim.x * gridDim.y;
  int flat = blockIdx.x + gridDim.x * blockIdx.y;
  int work = xcd_swz(flat, nwg);
  int n = work % gridDim.x, m = work / gridDim.x;
  gemm_core<false>(A, 1024, B, 1024, C, 1024, bias, 1.0f, 1024, m * 128, n * 128, 0);
}

// fused q/k/v projection straight from f32 inputs (gll-DMA staged);
// q,k -> head-major via cmode2 padded-LDS epilogue; v (z=2) -> vf (cmode 3)
__global__ __launch_bounds__(512) void gemm_proj(
    const float* __restrict__ q, const float* __restrict__ k,
    const float* __restrict__ v, const bf16* __restrict__ WT,
    const float* __restrict__ bias, bf16* __restrict__ qkout,
    bf16* __restrict__ vf) {
  int nwg = gridDim.x * gridDim.y * gridDim.z;
  int flat = blockIdx.x + gridDim.x * (blockIdx.y + gridDim.y * blockIdx.z);
  int work = xcd_swz(flat, nwg);
  int n = work % gridDim.x;
  int m = (work / gridDim.x) % gridDim.y;
  int z = work / (gridDim.x * gridDim.y);
  const float* A = (z == 0) ? q : ((z == 1) ? k : v);
  const bf16* B = WT + (long)z * 1048576;
  const float* bz = bias + z * 1024;
  void* C = (z == 2) ? (void*)vf : (void*)(qkout + (long)z * 4194304);
  float scale = (z == 0) ? 0.125f * LOG2E : 1.0f;
  gemm_core<true>(A, 1024, B, 1024, C, 1024, bz, scale, 1024, m * 128, n * 128,
                  z == 2 ? 3 : 2);
}

// ---------------- fused attention + avg_w (one launch, 512 thr) -------------
// 768 blocks x 512 thr = exactly 3 blocks/CU x 256 CU, one dispatch wave.
// blocks [0,512): attn, 8 waves x 16 t-rows (bh = bid&63, t0 = (bid>>6)*128).
// blocks [512,768): avg_w 128x128 tiles: 8(n) x 8(m) x 4(b) = 256 blocks.
__global__ __launch_bounds__(512) void attn_avg(
    const bf16* __restrict__ qh, const bf16* __restrict__ kh,
    const bf16* __restrict__ vf, bf16* __restrict__ attn_b,
    float* __restrict__ out_avg, float avg_scale) {
  __shared__ __align__(16) bf16 smem[16384];  // 32 KB arena
  int tid = threadIdx.x, w = tid >> 6, lane = tid & 63, r = lane & 15, g = lane >> 4;
  int fsw = (r >> 1) & 3;

  if (blockIdx.x >= 512) {
    // ---------- avg_w: C[bb][t][s] = avg_scale * sum_e qh[t][e] kh[s][e] ----
    // 128x128 tile, 8 waves; strided K: e=h*64+d -> off(k)=(k>>6)*65536+(k&63).
    bf16* sA = smem;            // [2][4096]
    bf16* sB = smem + 8192;     // [2][4096]
    int work = xcd_swz(blockIdx.x - 512, 256);
    int n0 = (work & 7) * 128;
    int m0 = ((work >> 3) & 7) * 128;
    int bb = work >> 6;         // 0..3
    int mq = (w >> 1) * 32, nq = (w & 1) * 64;
    int srow = w * 16 + (lane >> 2);
    int scol = ((lane & 3) ^ ((srow >> 1) & 3)) * 8;
    const bf16* As = qh + (long)bb * 1048576 + (long)(m0 + srow) * 64 + scol;
    const bf16* Bs = kh + (long)bb * 1048576 + (long)(n0 + srow) * 64 + scol;

    f32x4 acc[2][4];
#pragma unroll
    for (int mi = 0; mi < 2; mi++)
#pragma unroll
      for (int ni = 0; ni < 4; ni++) acc[mi][ni] = (f32x4){0.f, 0.f, 0.f, 0.f};

    gll16(As, &sA[w * 512]);
    gll16(Bs, &sB[w * 512]);
    __syncthreads();
    int cur = 0;
    for (int k0 = 0; k0 < 1024; k0 += 32) {
      if (k0 + 32 < 1024) {
        int kn = k0 + 32;
        long off = ((long)(kn >> 6)) * 65536 + (kn & 63);
        gll16(As + off, &sA[(cur ^ 1) * 4096 + w * 512]);
        gll16(Bs + off, &sB[(cur ^ 1) * 4096 + w * 512]);
      }
      bf16x8 af[2], bfr[4];
#pragma unroll
      for (int mi = 0; mi < 2; mi++)
        af[mi] = *(bf16x8*)&sA[cur * 4096 + (mq + mi * 16 + r) * 32 + 8 * (g ^ fsw)];
#pragma unroll
      for (int ni = 0; ni < 4; ni++)
        bfr[ni] = *(bf16x8*)&sB[cur * 4096 + (nq + ni * 16 + r) * 32 + 8 * (g ^ fsw)];
#pragma unroll
      for (int mi = 0; mi < 2; mi++)
#pragma unroll
        for (int ni = 0; ni < 4; ni++)
          acc[mi][ni] = __builtin_amdgcn_mfma_f32_16x16x32_bf16(af[mi], bfr[ni], acc[mi][ni], 0, 0, 0);
      __syncthreads();
      cur ^= 1;
    }
#pragma unroll
    for (int mi = 0; mi < 2; mi++)
#pragma unroll
      for (int ni = 0; ni < 4; ni++) {
        int col = n0 + nq + ni * 16 + r;
#pragma unroll
        for (int j = 0; j < 4; j++) {
          int row = m0 + mq + mi * 16 + g * 4 + j;
          out_avg[(long)bb * 1048576 + (long)row * 1024 + col] = acc[mi][ni][j] * avg_scale;
        }
      }
    return;
  }

  // ---------- attn: 8 waves, 16 t-rows/wave, full-S sweep ----------
  bf16* sK = smem;            // [2][4096]
  bf16* sV = smem + 8192;     // [2][4096]
  int bh = blockIdx.x & 63;
  int b = bh >> 4, h = bh & 15;
  int t0 = (blockIdx.x >> 6) * 128;
  int tw = t0 + w * 16;

  const bf16* qrow = qh + ((long)bh * 1024 + tw + r) * 64;
  bf16x8 aq0 = *(const bf16x8*)(qrow + g * 8);
  bf16x8 aq1 = *(const bf16x8*)(qrow + 32 + g * 8);

  float sp_acc = 0.f, sn_acc = 0.f;
  f32x4 o[4];
#pragma unroll
  for (int d = 0; d < 4; d++) o[d] = (f32x4){0.f, 0.f, 0.f, 0.f};

  const bf16* kbh = kh + (long)bh * 65536;
  const bf16* vbh = vf + (long)bh * 65536;

  // wave w stages K rows w*8..w*8+7 (src chunk XOR row&7) and V chunk w*512;
  // both advance 4096 elems per s-tile. (1 gll each per wave.)
  int krow = w * 8 + (lane >> 3);
  const bf16* ksrc = kbh + (long)krow * 64 + 8 * ((lane & 7) ^ (krow & 7));
  const bf16* vsrc = vbh + w * 512 + lane * 8;
  int c0 = 8 * (g ^ (r & 7));
  int c1 = 8 * ((g + 4) ^ (r & 7));

  gll16(ksrc, &sK[w * 512]);
  gll16(vsrc, &sV[w * 512]);
  __syncthreads();
  int cur = 0;
#pragma unroll 1
  for (int st = 0; st < 16; st++) {
    if (st < 15) {
      gll16(ksrc + (st + 1) * 4096, &sK[(cur ^ 1) * 4096 + w * 512]);
      gll16(vsrc + (st + 1) * 4096, &sV[(cur ^ 1) * 4096 + w * 512]);
    }
    f32x4 sc4[4];
#pragma unroll
    for (int sf = 0; sf < 4; sf++) {
      int row = sf * 16 + r;
      bf16x8 k0 = *(const bf16x8*)&sK[cur * 4096 + row * 64 + c0];
      bf16x8 k1 = *(const bf16x8*)&sK[cur * 4096 + row * 64 + c1];
      f32x4 z = (f32x4){0.f, 0.f, 0.f, 0.f};
      z = __builtin_amdgcn_mfma_f32_16x16x32_bf16(k0, aq0, z, 0, 0, 0);
      z = __builtin_amdgcn_mfma_f32_16x16x32_bf16(k1, aq1, z, 0, 0, 0);
      sc4[sf] = z;
    }
    bf16x8 pP[2], pN[2];
#pragma unroll
    for (int sf = 0; sf < 4; sf++)
#pragma unroll
      for (int j = 0; j < 4; j++) {
        float e = __builtin_amdgcn_exp2f(sc4[sf][j]);
        sp_acc += e;
        pP[sf >> 1][(sf & 1) * 4 + j] = (bf16)e;
        float f = __builtin_amdgcn_exp2f(-sc4[sf][j]);
        sn_acc += f;
        pN[sf >> 1][(sf & 1) * 4 + j] = (bf16)f;
      }
#pragma unroll
    for (int c = 0; c < 2; c++)
#pragma unroll
      for (int dblk = 0; dblk < 4; dblk++) {
        bf16x8 vv = *(const bf16x8*)&sV[cur * 4096 + (c * 4 + dblk) * 512 + lane * 8];
        o[dblk] = __builtin_amdgcn_mfma_f32_16x16x32_bf16(
            vv, (dblk < 2) ? pP[c] : pN[c], o[dblk], 0, 0, 0);
      }
    __syncthreads();
    cur ^= 1;
  }

  sp_acc += __shfl_xor(sp_acc, 16); sp_acc += __shfl_xor(sp_acc, 32);
  sn_acc += __shfl_xor(sn_acc, 16); sn_acc += __shfl_xor(sn_acc, 32);
  float rlp = 1.f / sp_acc, rln = 1.f / sn_acc;
  long obase = ((long)(tw + r) * 4 + b) * 1024 + h * 64;
#pragma unroll
  for (int dblk = 0; dblk < 4; dblk++) {
    float rl = (dblk < 2) ? rlp : rln;
    bf16x4 ov;
#pragma unroll
    for (int j = 0; j < 4; j++) ov[j] = (bf16)(o[dblk][j] * rl);
    *(bf16x4*)&attn_b[obase + (dblk >> 1) * 32 + (dblk & 1) * 16 + g * 4] = ov;
  }
}

// ---------------- launcher ----------------
extern "C" void kernel_launch(void* const* d_in, const int* in_sizes, int n_in,
                              void* d_out, int out_size, void* d_ws, size_t ws_size,
                              hipStream_t stream) {
  (void)in_sizes; (void)n_in; (void)out_size; (void)ws_size;
  const float* query = (const float*)d_in[0];
  const float* key   = (const float*)d_in[1];
  const float* value = (const float*)d_in[2];
  const float* W     = (const float*)d_in[3];
  const float* bias  = (const float*)d_in[4];
  const float* out_w = (const float*)d_in[5];
  const float* out_b = (const float*)d_in[6];

  char* ws = (char*)d_ws;
  const long MB = 1 << 20;
  bf16* qh  = (bf16*)(ws + 0 * MB);
  bf16* kh  = (bf16*)(ws + 8 * MB);
  bf16* vf  = (bf16*)(ws + 24 * MB);
  bf16* ab  = (bf16*)(ws + 32 * MB);
  bf16* WT  = (bf16*)(ws + 40 * MB);
  bf16* owb = (bf16*)(ws + 46 * MB);
  float* out_attn = (float*)d_out;
  float* out_avg  = (float*)d_out + (size_t)4 * 1024 * 1024;

  // prep: W transpose + out_w conversion only (q/k/v consumed directly by proj)
  prep_all<<<dim3(1792), 256, 0, stream>>>(W, out_w, WT, owb);

  // projections straight from f32 inputs: q,k -> head-major; v -> vf fragment
  gemm_proj<<<dim3(8, 32, 3), 512, 0, stream>>>(query, key, value, WT, bias, qh, vf);

  // fused: attention (blocks 0..511) + avg_w GEMM (blocks 512..767)
  attn_avg<<<dim3(768), 512, 0, stream>>>(qh, kh, vf, ab, out_avg,
                                          1.f / (16.f * LOG2E));

  // out projection: C = attn @ out_w^T + out_b
  gemm_out<<<dim3(8, 32), 512, 0, stream>>>(ab, owb, out_attn, out_b);
}

// Round 24
// 101.573 us; speedup vs baseline: 1.0334x; 1.0027x over previous
//
#include <hip/hip_runtime.h>
#include <hip/hip_bf16.h>

// Problem constants: E=1024, H=16, HD=64, T=1024, B=4, S=1024.
// d_out: attn(T,B,E) f32 [4M floats] then avg_w(B,T,S) f32 [4M floats].
// ws layout (bytes): qh 0..8M (head-major [bh][t][64], q pre-scaled 0.125*log2e),
//   kh 8..16M, vf 24..32M (frag-swizzled V, proj cmode3 LDS-coalesced epilogue),
//   ab 32..40M, WT 40..46M, owb 46..48M.
// q/k/v f32 inputs consumed DIRECTLY by gemm_proj via global_load_lds into f32
// LDS tiles (chunk-XOR swizzle c^=row&7; conversion at fragment-read).
// avg_w computed inside the attn launch: 768 blocks x 512 thr = 3 blocks/CU.
// out-proj: 128x64 tiles -> 512 blocks = 2 blocks/CU (cross-block drain overlap).

typedef __bf16 bf16;
typedef float f32x4 __attribute__((ext_vector_type(4)));
typedef float float4v __attribute__((ext_vector_type(4)));
typedef bf16 bf16x8 __attribute__((ext_vector_type(8)));
typedef bf16 bf16x4 __attribute__((ext_vector_type(4)));

#define LOG2E 1.4426950408889634f

// async global->LDS, 16B/lane; dst base wave-uniform (HW adds lane*16).
__device__ __forceinline__ void gll16(const void* g, void* l) {
  __builtin_amdgcn_global_load_lds(
      (const __attribute__((address_space(1))) void*)g,
      (__attribute__((address_space(3))) void*)l, 16, 0, 0);
}

// XCD-chunked swizzle: consecutive works (sharing an A-panel) land on one XCD.
__device__ __forceinline__ int xcd_swz(int flat, int nwg) {
  int q = nwg >> 3;
  return (flat & 7) * q + (flat >> 3);
}

__device__ __forceinline__ bf16x4 cvt4(float4v v) {
  bf16x4 b = { (bf16)v.x, (bf16)v.y, (bf16)v.z, (bf16)v.w };
  return b;
}

// ---------------- prep kernel (W transpose + out_w conv only) ----------------
__global__ __launch_bounds__(256) void prep_all(
    const float* __restrict__ W, const float* __restrict__ out_w,
    bf16* __restrict__ WT, bf16* __restrict__ owb) {
  __shared__ bf16 tile[64][72];
  int bid = blockIdx.x;
  if (bid >= 768) {  // out_w conversion: 1024 blocks
    int i = ((bid - 768) * 256 + (int)threadIdx.x) * 4;
    float4v v = *(const float4v*)(out_w + i);
    *(bf16x4*)&owb[i] = cvt4(v);
    return;
  }
  // W transpose: dst[sec][j][i] = (bf16) src[sec*1024 + i][j]
  int sec = bid >> 8, bx = bid & 15, by = (bid >> 4) & 15;
  int i0 = by * 64, j0 = bx * 64;
  const float* s = W + (long)sec * 1048576;
  bf16* d = WT + (long)sec * 1048576;
  int t = threadIdx.x;
#pragma unroll
  for (int p = 0; p < 4; p++) {
    int ri = (t >> 4) + p * 16, cj = (t & 15) * 4;
    float4v vv = *(const float4v*)(s + (long)(i0 + ri) * 1024 + j0 + cj);
    *(bf16x4*)&tile[ri][cj] = cvt4(vv);
  }
  __syncthreads();
#pragma unroll
  for (int p = 0; p < 4; p++) {
    int rj = (t >> 4) + p * 16, ci = (t & 15) * 4;
    bf16x4 bv = { tile[ci][rj], tile[ci + 1][rj], tile[ci + 2][rj], tile[ci + 3][rj] };
    *(bf16x4*)&d[(long)(j0 + rj) * 1024 + i0 + ci] = bv;
  }
}

// ---------------- unified NT GEMM core (512 thr, 8 waves, 128x128) ----------
// R11-best loop: dbuf, stage(next) BEFORE compute(cur), ONE __syncthreads per
// k-step; all staging via global_load_lds. AF32: A f32 staged into f32 LDS
// tiles with CHUNK-XOR swizzle (float4-chunk c stored at c^(row&7); read at
// (2g)^(r&7), (2g+1)^(r&7)); converted f32->bf16 at fragment read.
// cmode: 2 bf16 head-major via PADDED-LDS epilogue, 3 vf fragment (LDS epi).
template <bool AF32>
__device__ __forceinline__ void gemm_core(
    const void* __restrict__ Av, long lda,
    const bf16* __restrict__ B, long ldb,
    void* __restrict__ C, long ldc,
    const float* __restrict__ bias, float scale, int K,
    int m0, int n0, int cmode) {
  __shared__ bf16 smem[AF32 ? 24576 : 16384];
  float* sAf = (float*)smem;                       // AF32: [2][4096] f32
  bf16* sBb = smem + (AF32 ? 16384 : 8192);        // [2][4096] bf16
  int t = threadIdx.x;
  int w = t >> 6, lane = t & 63, r = lane & 15, g = lane >> 4;
  int mq = (w >> 1) * 32, nq = (w & 1) * 64;
  int srow = w * 16 + (lane >> 2);
  int scol = ((lane & 3) ^ ((srow >> 1) & 3)) * 8;
  int fsw = (r >> 1) & 3;
  const bf16* Bs = B + (long)(n0 + srow) * ldb + scol;
  const bf16* As = (const bf16*)Av + (long)(m0 + srow) * lda + scol;  // !AF32
  int aro = lane >> 3;
  int acolf = 4 * ((lane & 7) ^ aro);
  const float* Af = (const float*)Av + (long)(m0 + w * 16 + aro) * lda + acolf;

  f32x4 acc[2][4];
#pragma unroll
  for (int mi = 0; mi < 2; mi++)
#pragma unroll
    for (int ni = 0; ni < 4; ni++) acc[mi][ni] = (f32x4){0.f, 0.f, 0.f, 0.f};

  auto stage = [&](int buf, int k) {
    if (AF32) {
      gll16(Af + k, sAf + buf * 4096 + w * 512);
      gll16(Af + 8 * lda + k, sAf + buf * 4096 + w * 512 + 256);
    } else {
      gll16(As + k, &smem[buf * 4096 + w * 512]);
    }
    gll16(Bs + k, &sBb[buf * 4096 + w * 512]);
  };
  stage(0, 0);
  __syncthreads();
  int cur = 0;
  for (int k0 = 0; k0 < K; k0 += 32) {
    if (k0 + 32 < K) stage(cur ^ 1, k0 + 32);
    bf16x8 af[2], bfr[4];
    if (AF32) {
      int rk = r & 7;
#pragma unroll
      for (int mi = 0; mi < 2; mi++) {
        int row = mq + mi * 16 + r;
        const float* pa = sAf + cur * 4096 + row * 32;
        float4v lo = *(const float4v*)(pa + 4 * ((2 * g) ^ rk));
        float4v hi = *(const float4v*)(pa + 4 * ((2 * g + 1) ^ rk));
        bf16x4 l4 = cvt4(lo), h4 = cvt4(hi);
        bf16x8 a = { l4[0], l4[1], l4[2], l4[3], h4[0], h4[1], h4[2], h4[3] };
        af[mi] = a;
      }
    } else {
#pragma unroll
      for (int mi = 0; mi < 2; mi++)
        af[mi] = *(bf16x8*)&smem[cur * 4096 + (mq + mi * 16 + r) * 32 + 8 * (g ^ fsw)];
    }
#pragma unroll
    for (int ni = 0; ni < 4; ni++)
      bfr[ni] = *(bf16x8*)&sBb[cur * 4096 + (nq + ni * 16 + r) * 32 + 8 * (g ^ fsw)];
#pragma unroll
    for (int mi = 0; mi < 2; mi++)
#pragma unroll
      for (int ni = 0; ni < 4; ni++)
        acc[mi][ni] = __builtin_amdgcn_mfma_f32_16x16x32_bf16(af[mi], bfr[ni], acc[mi][ni], 0, 0, 0);
    __syncthreads();
    cur ^= 1;
  }

  if (cmode == 2) {
    // head-major: PADDED image [8][32][80]; coalesced 1KB/wave global stores.
#pragma unroll
    for (int mi = 0; mi < 2; mi++) {
      int tl = (mq >> 2) + mi * 4 + g;
#pragma unroll
      for (int ni = 0; ni < 4; ni++) {
        int cl = nq + ni * 16 + r;
        float bv = bias ? bias[n0 + cl] : 0.f;
        int chunkb = (nq >> 6) * 2560 + tl * 80 + ni * 16 + r;
#pragma unroll
        for (int j = 0; j < 4; j++) {
          float val = (acc[mi][ni][j] + bv) * scale;
          smem[j * 5120 + chunkb] = (bf16)val;
        }
      }
    }
    __syncthreads();
    {
      int b_ = w >> 1, hl = w & 1;
      long gbase = ((long)(b_ * 16 + (n0 >> 6) + hl)) * 65536 + (long)(m0 >> 2) * 64;
#pragma unroll
      for (int it = 0; it < 4; it++) {
        bf16x8 v = *(bf16x8*)&smem[w * 2560 + (it * 8 + (lane >> 3)) * 80 + (lane & 7) * 8];
        *(bf16x8*)&((bf16*)C)[gbase + it * 512 + lane * 8] = v;
      }
    }
    return;
  }

  // cmode == 3: acc -> LDS in vf order -> coalesced 1KB/wave stores.
#pragma unroll
  for (int mi = 0; mi < 2; mi++) {
    int s32 = (mq >> 2) + mi * 4 + g;
    int gq = (s32 >> 2) & 3;
    int u = ((s32 >> 4) << 2) | (s32 & 3);
#pragma unroll
    for (int ni = 0; ni < 4; ni++) {
      int col = n0 + nq + ni * 16 + r;
      float bv = bias ? bias[col] : 0.f;
      int clbase = ((nq >> 5) + (ni >> 1)) * 2 + (ni & 1);
#pragma unroll
      for (int j = 0; j < 4; j++) {
        float val = (acc[mi][ni][j] + bv) * scale;
        smem[(j * 8 + clbase) * 512 + (gq * 16 + r) * 8 + u] = (bf16)val;
      }
    }
  }
  __syncthreads();
  {
    int sc_ = m0 >> 7;
    int hh0 = (n0 & 511) >> 5;
    int half = n0 >> 9;
#pragma unroll
    for (int c = 0; c < 4; c++) {
      int cl = w * 4 + c;
      int b_ = cl >> 3, hl = (cl >> 1) & 3, dl = cl & 1;
      long chunk = ((long)(b_ * 16 + hh0 + hl) * 32 + sc_) * 4 + half * 2 + dl;
      bf16x8 v = *(bf16x8*)&smem[cl * 512 + lane * 8];
      *(bf16x8*)&((bf16*)C)[(chunk << 9) + lane * 8] = v;
    }
  }
}

// out-projection: 128x64 tiles, 512 blocks = 2 blocks/CU (drain overlap).
// 8 waves: mq=(w>>1)*32 covers 128 m, nq=(w&1)*32 covers 64 n; acc[2][2].
// B tile [64][32] staged by waves 0..3 only.
__global__ __launch_bounds__(512) void gemm_out(
    const bf16* __restrict__ A, const bf16* __restrict__ B,
    float* __restrict__ C, const float* __restrict__ bias) {
  __shared__ bf16 sA[2][4096];
  __shared__ bf16 sB[2][2048];
  int nwg = gridDim.x * gridDim.y;
  int flat = blockIdx.x + gridDim.x * blockIdx.y;
  int work = xcd_swz(flat, nwg);
  int n0 = (work % gridDim.x) * 64;
  int m0 = (work / gridDim.x) * 128;
  int t = threadIdx.x;
  int w = t >> 6, lane = t & 63, r = lane & 15, g = lane >> 4;
  int mq = (w >> 1) * 32, nq = (w & 1) * 32;
  int srow = w * 16 + (lane >> 2);
  int scol = ((lane & 3) ^ ((srow >> 1) & 3)) * 8;
  int fsw = (r >> 1) & 3;
  const bf16* As = A + (long)(m0 + srow) * 1024 + scol;
  const bf16* Bs = B + (long)(n0 + srow) * 1024 + scol;  // valid for w<4

  f32x4 acc[2][2];
#pragma unroll
  for (int mi = 0; mi < 2; mi++)
#pragma unroll
    for (int ni = 0; ni < 2; ni++) acc[mi][ni] = (f32x4){0.f, 0.f, 0.f, 0.f};

  auto stage = [&](int buf, int k) {
    gll16(As + k, &sA[buf][w * 512]);
    if (w < 4) gll16(Bs + k, &sB[buf][w * 512]);
  };
  stage(0, 0);
  __syncthreads();
  int cur = 0;
  for (int k0 = 0; k0 < 1024; k0 += 32) {
    if (k0 + 32 < 1024) stage(cur ^ 1, k0 + 32);
    bf16x8 af[2], bfr[2];
#pragma unroll
    for (int mi = 0; mi < 2; mi++)
      af[mi] = *(bf16x8*)&sA[cur][(mq + mi * 16 + r) * 32 + 8 * (g ^ fsw)];
#pragma unroll
    for (int ni = 0; ni < 2; ni++)
      bfr[ni] = *(bf16x8*)&sB[cur][(nq + ni * 16 + r) * 32 + 8 * (g ^ fsw)];
#pragma unroll
    for (int mi = 0; mi < 2; mi++)
#pragma unroll
      for (int ni = 0; ni < 2; ni++)
        acc[mi][ni] = __builtin_amdgcn_mfma_f32_16x16x32_bf16(af[mi], bfr[ni], acc[mi][ni], 0, 0, 0);
    __syncthreads();
    cur ^= 1;
  }

#pragma unroll
  for (int mi = 0; mi < 2; mi++)
#pragma unroll
    for (int ni = 0; ni < 2; ni++) {
      int col = n0 + nq + ni * 16 + r;
      float bv = bias[col];
#pragma unroll
      for (int j = 0; j < 4; j++) {
        int row = m0 + mq + mi * 16 + g * 4 + j;
        C[(long)row * 1024 + col] = acc[mi][ni][j] + bv;
      }
    }
}

// fused q/k/v projection straight from f32 inputs (gll-DMA staged);
// q,k -> head-major via cmode2 padded-LDS epilogue; v (z=2) -> vf (cmode 3)
__global__ __launch_bounds__(512) void gemm_proj(
    const float* __restrict__ q, const float* __restrict__ k,
    const float* __restrict__ v, const bf16* __restrict__ WT,
    const float* __restrict__ bias, bf16* __restrict__ qkout,
    bf16* __restrict__ vf) {
  int nwg = gridDim.x * gridDim.y * gridDim.z;
  int flat = blockIdx.x + gridDim.x * (blockIdx.y + gridDim.y * blockIdx.z);
  int work = xcd_swz(flat, nwg);
  int n = work % gridDim.x;
  int m = (work / gridDim.x) % gridDim.y;
  int z = work / (gridDim.x * gridDim.y);
  const float* A = (z == 0) ? q : ((z == 1) ? k : v);
  const bf16* B = WT + (long)z * 1048576;
  const float* bz = bias + z * 1024;
  void* C = (z == 2) ? (void*)vf : (void*)(qkout + (long)z * 4194304);
  float scale = (z == 0) ? 0.125f * LOG2E : 1.0f;
  gemm_core<true>(A, 1024, B, 1024, C, 1024, bz, scale, 1024, m * 128, n * 128,
                  z == 2 ? 3 : 2);
}

// ---------------- fused attention + avg_w (one launch, 512 thr) -------------
// 768 blocks x 512 thr = exactly 3 blocks/CU x 256 CU, one dispatch wave.
// blocks [0,512): attn, 8 waves x 16 t-rows (bh = bid&63, t0 = (bid>>6)*128).
// blocks [512,768): avg_w 128x128 tiles: 8(n) x 8(m) x 4(b) = 256 blocks.
__global__ __launch_bounds__(512) void attn_avg(
    const bf16* __restrict__ qh, const bf16* __restrict__ kh,
    const bf16* __restrict__ vf, bf16* __restrict__ attn_b,
    float* __restrict__ out_avg, float avg_scale) {
  __shared__ __align__(16) bf16 smem[16384];  // 32 KB arena
  int tid = threadIdx.x, w = tid >> 6, lane = tid & 63, r = lane & 15, g = lane >> 4;
  int fsw = (r >> 1) & 3;

  if (blockIdx.x >= 512) {
    // ---------- avg_w: C[bb][t][s] = avg_scale * sum_e qh[t][e] kh[s][e] ----
    bf16* sA = smem;            // [2][4096]
    bf16* sB = smem + 8192;     // [2][4096]
    int work = xcd_swz(blockIdx.x - 512, 256);
    int n0 = (work & 7) * 128;
    int m0 = ((work >> 3) & 7) * 128;
    int bb = work >> 6;         // 0..3
    int mq = (w >> 1) * 32, nq = (w & 1) * 64;
    int srow = w * 16 + (lane >> 2);
    int scol = ((lane & 3) ^ ((srow >> 1) & 3)) * 8;
    const bf16* As = qh + (long)bb * 1048576 + (long)(m0 + srow) * 64 + scol;
    const bf16* Bs = kh + (long)bb * 1048576 + (long)(n0 + srow) * 64 + scol;

    f32x4 acc[2][4];
#pragma unroll
    for (int mi = 0; mi < 2; mi++)
#pragma unroll
      for (int ni = 0; ni < 4; ni++) acc[mi][ni] = (f32x4){0.f, 0.f, 0.f, 0.f};

    gll16(As, &sA[w * 512]);
    gll16(Bs, &sB[w * 512]);
    __syncthreads();
    int cur = 0;
    for (int k0 = 0; k0 < 1024; k0 += 32) {
      if (k0 + 32 < 1024) {
        int kn = k0 + 32;
        long off = ((long)(kn >> 6)) * 65536 + (kn & 63);
        gll16(As + off, &sA[(cur ^ 1) * 4096 + w * 512]);
        gll16(Bs + off, &sB[(cur ^ 1) * 4096 + w * 512]);
      }
      bf16x8 af[2], bfr[4];
#pragma unroll
      for (int mi = 0; mi < 2; mi++)
        af[mi] = *(bf16x8*)&sA[cur * 4096 + (mq + mi * 16 + r) * 32 + 8 * (g ^ fsw)];
#pragma unroll
      for (int ni = 0; ni < 4; ni++)
        bfr[ni] = *(bf16x8*)&sB[cur * 4096 + (nq + ni * 16 + r) * 32 + 8 * (g ^ fsw)];
#pragma unroll
      for (int mi = 0; mi < 2; mi++)
#pragma unroll
        for (int ni = 0; ni < 4; ni++)
          acc[mi][ni] = __builtin_amdgcn_mfma_f32_16x16x32_bf16(af[mi], bfr[ni], acc[mi][ni], 0, 0, 0);
      __syncthreads();
      cur ^= 1;
    }
#pragma unroll
    for (int mi = 0; mi < 2; mi++)
#pragma unroll
      for (int ni = 0; ni < 4; ni++) {
        int col = n0 + nq + ni * 16 + r;
#pragma unroll
        for (int j = 0; j < 4; j++) {
          int row = m0 + mq + mi * 16 + g * 4 + j;
          out_avg[(long)bb * 1048576 + (long)row * 1024 + col] = acc[mi][ni][j] * avg_scale;
        }
      }
    return;
  }

  // ---------- attn: 8 waves, 16 t-rows/wave, full-S sweep ----------
  bf16* sK = smem;            // [2][4096]
  bf16* sV = smem + 8192;     // [2][4096]
  int bh = blockIdx.x & 63;
  int b = bh >> 4, h = bh & 15;
  int t0 = (blockIdx.x >> 6) * 128;
  int tw = t0 + w * 16;

  const bf16* qrow = qh + ((long)bh * 1024 + tw + r) * 64;
  bf16x8 aq0 = *(const bf16x8*)(qrow + g * 8);
  bf16x8 aq1 = *(const bf16x8*)(qrow + 32 + g * 8);

  float sp_acc = 0.f, sn_acc = 0.f;
  f32x4 o[4];
#pragma unroll
  for (int d = 0; d < 4; d++) o[d] = (f32x4){0.f, 0.f, 0.f, 0.f};

  const bf16* kbh = kh + (long)bh * 65536;
  const bf16* vbh = vf + (long)bh * 65536;

  int krow = w * 8 + (lane >> 3);
  const bf16* ksrc = kbh + (long)krow * 64 + 8 * ((lane & 7) ^ (krow & 7));
  const bf16* vsrc = vbh + w * 512 + lane * 8;
  int c0 = 8 * (g ^ (r & 7));
  int c1 = 8 * ((g + 4) ^ (r & 7));

  gll16(ksrc, &sK[w * 512]);
  gll16(vsrc, &sV[w * 512]);
  __syncthreads();
  int cur = 0;
#pragma unroll 1
  for (int st = 0; st < 16; st++) {
    if (st < 15) {
      gll16(ksrc + (st + 1) * 4096, &sK[(cur ^ 1) * 4096 + w * 512]);
      gll16(vsrc + (st + 1) * 4096, &sV[(cur ^ 1) * 4096 + w * 512]);
    }
    f32x4 sc4[4];
#pragma unroll
    for (int sf = 0; sf < 4; sf++) {
      int row = sf * 16 + r;
      bf16x8 k0 = *(const bf16x8*)&sK[cur * 4096 + row * 64 + c0];
      bf16x8 k1 = *(const bf16x8*)&sK[cur * 4096 + row * 64 + c1];
      f32x4 z = (f32x4){0.f, 0.f, 0.f, 0.f};
      z = __builtin_amdgcn_mfma_f32_16x16x32_bf16(k0, aq0, z, 0, 0, 0);
      z = __builtin_amdgcn_mfma_f32_16x16x32_bf16(k1, aq1, z, 0, 0, 0);
      sc4[sf] = z;
    }
    bf16x8 pP[2], pN[2];
#pragma unroll
    for (int sf = 0; sf < 4; sf++)
#pragma unroll
      for (int j = 0; j < 4; j++) {
        float e = __builtin_amdgcn_exp2f(sc4[sf][j]);
        sp_acc += e;
        pP[sf >> 1][(sf & 1) * 4 + j] = (bf16)e;
        float f = __builtin_amdgcn_exp2f(-sc4[sf][j]);
        sn_acc += f;
        pN[sf >> 1][(sf & 1) * 4 + j] = (bf16)f;
      }
#pragma unroll
    for (int c = 0; c < 2; c++)
#pragma unroll
      for (int dblk = 0; dblk < 4; dblk++) {
        bf16x8 vv = *(const bf16x8*)&sV[cur * 4096 + (c * 4 + dblk) * 512 + lane * 8];
        o[dblk] = __builtin_amdgcn_mfma_f32_16x16x32_bf16(
            vv, (dblk < 2) ? pP[c] : pN[c], o[dblk], 0, 0, 0);
      }
    __syncthreads();
    cur ^= 1;
  }

  sp_acc += __shfl_xor(sp_acc, 16); sp_acc += __shfl_xor(sp_acc, 32);
  sn_acc += __shfl_xor(sn_acc, 16); sn_acc += __shfl_xor(sn_acc, 32);
  float rlp = 1.f / sp_acc, rln = 1.f / sn_acc;
  long obase = ((long)(tw + r) * 4 + b) * 1024 + h * 64;
#pragma unroll
  for (int dblk = 0; dblk < 4; dblk++) {
    float rl = (dblk < 2) ? rlp : rln;
    bf16x4 ov;
#pragma unroll
    for (int j = 0; j < 4; j++) ov[j] = (bf16)(o[dblk][j] * rl);
    *(bf16x4*)&attn_b[obase + (dblk >> 1) * 32 + (dblk & 1) * 16 + g * 4] = ov;
  }
}

// ---------------- launcher ----------------
extern "C" void kernel_launch(void* const* d_in, const int* in_sizes, int n_in,
                              void* d_out, int out_size, void* d_ws, size_t ws_size,
                              hipStream_t stream) {
  (void)in_sizes; (void)n_in; (void)out_size; (void)ws_size;
  const float* query = (const float*)d_in[0];
  const float* key   = (const float*)d_in[1];
  const float* value = (const float*)d_in[2];
  const float* W     = (const float*)d_in[3];
  const float* bias  = (const float*)d_in[4];
  const float* out_w = (const float*)d_in[5];
  const float* out_b = (const float*)d_in[6];

  char* ws = (char*)d_ws;
  const long MB = 1 << 20;
  bf16* qh  = (bf16*)(ws + 0 * MB);
  bf16* kh  = (bf16*)(ws + 8 * MB);
  bf16* vf  = (bf16*)(ws + 24 * MB);
  bf16* ab  = (bf16*)(ws + 32 * MB);
  bf16* WT  = (bf16*)(ws + 40 * MB);
  bf16* owb = (bf16*)(ws + 46 * MB);
  float* out_attn = (float*)d_out;
  float* out_avg  = (float*)d_out + (size_t)4 * 1024 * 1024;

  // prep: W transpose + out_w conversion only (q/k/v consumed directly by proj)
  prep_all<<<dim3(1792), 256, 0, stream>>>(W, out_w, WT, owb);

  // projections straight from f32 inputs: q,k -> head-major; v -> vf fragment
  gemm_proj<<<dim3(8, 32, 3), 512, 0, stream>>>(query, key, value, WT, bias, qh, vf);

  // fused: attention (blocks 0..511) + avg_w GEMM (blocks 512..767)
  attn_avg<<<dim3(768), 512, 0, stream>>>(qh, kh, vf, ab, out_avg,
                                          1.f / (16.f * LOG2E));

  // out projection: C = attn @ out_w^T + out_b  (128x64 tiles, 2 blocks/CU)
  gemm_out<<<dim3(16, 32), 512, 0, stream>>>(ab, owb, out_attn, out_b);
}